// Round 1
// baseline (302.898 us; speedup 1.0000x reference)
//
#include <hip/hip_runtime.h>
#include <hip/hip_bf16.h>
#include <math.h>

typedef __hip_bfloat16 bf16;
typedef __attribute__((ext_vector_type(8))) short bf16x8;
typedef __attribute__((ext_vector_type(4))) float f32x4;

#define GPTR(p) ((const __attribute__((address_space(1))) void*)(p))
#define LPTR(p) ((__attribute__((address_space(3))) void*)(p))

__device__ __forceinline__ float b2f(short s) {
  unsigned int u = ((unsigned int)(unsigned short)s) << 16;
  float f; __builtin_memcpy(&f, &u, 4); return f;
}

// ---------------------------------------------------------------------------
// Merged fp32 -> bf16 conversion for all 5 MFMA operand tensors (1 dispatch).
// ---------------------------------------------------------------------------
__global__ __launch_bounds__(256) void cvt_all(
    const float* __restrict__ x,    const float* __restrict__ w_in,
    const float* __restrict__ w_out,const float* __restrict__ w1,
    const float* __restrict__ w2,
    bf16* __restrict__ xb,   bf16* __restrict__ winb, bf16* __restrict__ woutb,
    bf16* __restrict__ w1b,  bf16* __restrict__ w2b)
{
  const int b = blockIdx.x;
  const float* in; bf16* out; int base;
  if      (b <  4096) { in = x;     out = xb;    base = 0; }
  else if (b <  7168) { in = w_in;  out = winb;  base = 4096; }
  else if (b <  8192) { in = w_out; out = woutb; base = 7168; }
  else if (b < 12288) { in = w1;    out = w1b;   base = 8192; }
  else                { in = w2;    out = w2b;   base = 12288; }
  const int i = ((b - base) * 256 + threadIdx.x) * 4;
  const float4 f = *(const float4*)(in + i);
  ushort4 u;
  u.x = __bfloat16_as_ushort(__float2bfloat16(f.x));
  u.y = __bfloat16_as_ushort(__float2bfloat16(f.y));
  u.z = __bfloat16_as_ushort(__float2bfloat16(f.z));
  u.w = __bfloat16_as_ushort(__float2bfloat16(f.w));
  *(ushort4*)(out + i) = u;
}

__device__ __forceinline__ float gelu_fast(float v) {
  const float u  = 1.5957691216f * (v + 0.044715f * v * v * v);
  const float e  = __expf(u);
  return v * e / (e + 1.0f);
}

// ---------------------------------------------------------------------------
// 8-phase counted-vmcnt GEMM (T1+T2+T3+T4+T5 stack, learn_hip m201 template
// re-derived for BM=128 x BN=256 so every GEMM in this net gets a >=256-block
// grid with only 2 split-K partials):
//   C[M,N](bf16) = A[M,K](lda) * B[N,K]^T(ldb) [+bias][+GELU], split-K via z.
//   8 waves (2M x 4N), per-wave 64x64 output, BK=64.
//   LDS: 3 buffers x (A 16KB + B 32KB) = 144KB -> lookahead-2 pipeline:
//     compute tile t (buf t%3) | tile t+1 resident | tile t+2 in flight.
//   Per K-tile: 2 phases of {ds_reads + 3 staging issues -> s_barrier ->
//     lgkmcnt(0) -> sched_barrier(0) -> setprio(1) -> 16 MFMA -> setprio(0)}.
//   vmcnt(6) ONLY at the K-tile boundary (never 0 in steady state) => the 6
//   loads of tile t+2 stay in flight across the barrier (T4).
//   XOR swizzle byte^=((row&7)<<4), applied identically on the pre-swizzled
//   global source (linear global_load_lds dest) and the ds_read side.
//   Grids must tile M,N exactly (M%128==0, N%256==0); kchunk%64==0, >=128.
// ---------------------------------------------------------------------------
#define STAGE(bi, kt, j)                                                      \
  do {                                                                        \
    if ((j) < 4)                                                              \
      __builtin_amdgcn_global_load_lds(                                       \
          GPTR(B + (size_t)gsrcB[(j)] + ((kt) << 6)),                         \
          LPTR(&lds[(bi)][8192 + (j) * 4096 + ldsW]), 16, 0, 0);              \
    else                                                                      \
      __builtin_amdgcn_global_load_lds(                                       \
          GPTR(A + (size_t)gsrcA[(j) - 4] + ((kt) << 6)),                     \
          LPTR(&lds[(bi)][((j) - 4) * 4096 + ldsW]), 16, 0, 0);               \
  } while (0)

#define LDSRD(off) (*(const bf16x8*)((const char*)(&lds[bi][0]) + (off)))

template<int GELU, int RESID>   // RESID: 0 none, 1 fp32, 2 bf16
__global__ __launch_bounds__(512, 2) void gemm8p(
    const bf16* __restrict__ A, int lda,
    const bf16* __restrict__ B, int ldb,
    const float* __restrict__ bias,
    const void* __restrict__ Rv, int ldr,
    bf16* __restrict__ C, int ldc, long czstride,
    int kchunk)
{
  // per buffer: A [128 rows][64] bf16 @ 0, B [256 rows][64] bf16 @ 8192
  __shared__ __align__(16) bf16 lds[3][24576];

  const int t    = threadIdx.x;          // 0..511
  const int lane = t & 63;
  const int w    = t >> 6;               // 0..7
  const int wm   = w >> 2;               // 0..1  (64-row slice)
  const int wn   = w & 3;                // 0..3  (64-col slice)
  const int lr   = lane & 15;
  const int lq   = lane >> 4;

  // T1: bijective XCD swizzle (m204) over the flattened grid: consecutive
  // work ids (x fastest => shared A row-panels) land on the SAME XCD L2.
  const int gx   = gridDim.x, gy = gridDim.y;
  const int nwg  = gx * gy * gridDim.z;
  const int orig = blockIdx.x + gx * (blockIdx.y + gy * blockIdx.z);
  const int qq   = nwg >> 3, rr = nwg & 7;
  const int xcd  = orig & 7;
  const int wid  = (xcd < rr ? xcd * (qq + 1) : rr * (qq + 1) + (xcd - rr) * qq)
                 + (orig >> 3);
  const int n0 = (wid % gx) * 256;
  const int m0 = ((wid / gx) % gy) * 128;
  const int kz = wid / (gx * gy);

  A += (size_t)kz * kchunk;
  B += (size_t)kz * kchunk;
  C += (size_t)kz * czstride;

  const int NT = kchunk >> 6;

  // --- per-thread staging offsets (linear LDS dest, pre-swizzled gsrc) ---
  // round j: 8KB block; thread writes LDS bytes q=j*8192+t*16 (wave-uniform
  // base + lane*16 as global_load_lds requires); global src address carries
  // the same XOR involution so LDS[swz(p)] == G[p].
  int gsrcA[2], gsrcB[4];
  #pragma unroll
  for (int j = 0; j < 4; ++j) {
    const int q   = j * 8192 + t * 16;
    const int row = q >> 7;                       // 0..255
    const int qs  = q ^ ((row & 7) << 4);
    gsrcB[j] = (n0 + (qs >> 7)) * ldb + ((qs & 127) >> 1);
  }
  #pragma unroll
  for (int j = 0; j < 2; ++j) {
    const int q   = j * 8192 + t * 16;
    const int row = q >> 7;                       // 0..127
    const int qs  = q ^ ((row & 7) << 4);
    gsrcA[j] = (m0 + (qs >> 7)) * lda + ((qs & 127) >> 1);
  }
  const int ldsW = w * 512;                       // wave base (bf16 units)

  // --- per-thread ds_read byte offsets (swizzled) ---
  int aoff[4][2], boff[4][2];
  #pragma unroll
  for (int mi = 0; mi < 4; ++mi) {
    const int row = wm * 64 + mi * 16 + lr;
    #pragma unroll
    for (int ks = 0; ks < 2; ++ks)
      aoff[mi][ks] = (row * 128 + ks * 64 + lq * 16) ^ ((row & 7) << 4);
  }
  #pragma unroll
  for (int ni = 0; ni < 4; ++ni) {
    const int row = wn * 64 + ni * 16 + lr;
    #pragma unroll
    for (int ks = 0; ks < 2; ++ks)
      boff[ni][ks] = 16384 + ((row * 128 + ks * 64 + lq * 16) ^ ((row & 7) << 4));
  }

  f32x4 acc[4][4];
  #pragma unroll
  for (int mi = 0; mi < 4; ++mi)
    #pragma unroll
    for (int ni = 0; ni < 4; ++ni)
      acc[mi][ni] = (f32x4){0.f, 0.f, 0.f, 0.f};

  // --- prologue: issue tiles 0 and 1; wait tile 0 resident (vmcnt(6)) ---
  STAGE(0, 0, 0); STAGE(0, 0, 1); STAGE(0, 0, 2);
  STAGE(0, 0, 3); STAGE(0, 0, 4); STAGE(0, 0, 5);
  if (NT > 1) {
    STAGE(1, 1, 0); STAGE(1, 1, 1); STAGE(1, 1, 2);
    STAGE(1, 1, 3); STAGE(1, 1, 4); STAGE(1, 1, 5);
    asm volatile("s_waitcnt vmcnt(6)" ::: "memory");
  } else {
    asm volatile("s_waitcnt vmcnt(0)" ::: "memory");
  }
  __builtin_amdgcn_s_barrier();

  for (int kt = 0; kt < NT; ++kt) {
    const int  bi = kt % 3;
    const int  si = (kt + 2) % 3;
    const bool st = (kt + 2) < NT;

    bf16x8 af[2][2], bq[4][2];

    // ---- phase 0: A m0-1 + all B (12 ds_reads) | stage rounds 0-2 ----
    #pragma unroll
    for (int mi = 0; mi < 2; ++mi) {
      af[mi][0] = LDSRD(aoff[mi][0]);
      af[mi][1] = LDSRD(aoff[mi][1]);
    }
    #pragma unroll
    for (int ni = 0; ni < 4; ++ni) {
      bq[ni][0] = LDSRD(boff[ni][0]);
      bq[ni][1] = LDSRD(boff[ni][1]);
    }
    if (st) { STAGE(si, kt + 2, 0); STAGE(si, kt + 2, 1); STAGE(si, kt + 2, 2); }
    __builtin_amdgcn_s_barrier();
    asm volatile("s_waitcnt lgkmcnt(0)" ::: "memory");
    __builtin_amdgcn_sched_barrier(0);          // rule #18: pin MFMA after wait
    __builtin_amdgcn_s_setprio(1);
    #pragma unroll
    for (int mi = 0; mi < 2; ++mi)
      #pragma unroll
      for (int ni = 0; ni < 4; ++ni)
        #pragma unroll
        for (int ks = 0; ks < 2; ++ks)
          acc[mi][ni] = __builtin_amdgcn_mfma_f32_16x16x32_bf16(
              af[mi][ks], bq[ni][ks], acc[mi][ni], 0, 0, 0);
    __builtin_amdgcn_s_setprio(0);
    __builtin_amdgcn_s_barrier();

    // ---- phase 1: A m2-3 (4 ds_reads) | stage rounds 3-5 | tile boundary ----
    #pragma unroll
    for (int mi = 0; mi < 2; ++mi) {
      af[mi][0] = LDSRD(aoff[2 + mi][0]);
      af[mi][1] = LDSRD(aoff[2 + mi][1]);
    }
    if (st) { STAGE(si, kt + 2, 3); STAGE(si, kt + 2, 4); STAGE(si, kt + 2, 5); }
    __builtin_amdgcn_s_barrier();
    asm volatile("s_waitcnt lgkmcnt(0)" ::: "memory");
    __builtin_amdgcn_sched_barrier(0);
    __builtin_amdgcn_s_setprio(1);
    #pragma unroll
    for (int mi = 0; mi < 2; ++mi)
      #pragma unroll
      for (int ni = 0; ni < 4; ++ni)
        #pragma unroll
        for (int ks = 0; ks < 2; ++ks)
          acc[2 + mi][ni] = __builtin_amdgcn_mfma_f32_16x16x32_bf16(
              af[mi][ks], bq[ni][ks], acc[2 + mi][ni], 0, 0, 0);
    __builtin_amdgcn_s_setprio(0);
    // T4: counted wait — tile kt+1 resident, tile kt+2's 6 loads in flight.
    if (kt < NT - 2)       asm volatile("s_waitcnt vmcnt(6)" ::: "memory");
    else if (kt == NT - 2) asm volatile("s_waitcnt vmcnt(0)" ::: "memory");
    __builtin_amdgcn_s_barrier();
  }

  // ---- epilogue: C/D layout col=lane&15, row=(lane>>4)*4+i ----
  #pragma unroll
  for (int ni = 0; ni < 4; ++ni) {
    const int col = n0 + wn * 64 + ni * 16 + lr;
    const float bv = bias ? bias[col] : 0.f;
    #pragma unroll
    for (int mi = 0; mi < 4; ++mi) {
      const int rowb = m0 + wm * 64 + mi * 16 + lq * 4;
      #pragma unroll
      for (int i = 0; i < 4; ++i) {
        float v = acc[mi][ni][i] + bv;
        if (GELU) v = gelu_fast(v);
        if (RESID == 1) v += ((const float*)Rv)[(size_t)(rowb + i) * ldr + col];
        if (RESID == 2) v += __bfloat162float(((const bf16*)Rv)[(size_t)(rowb + i) * ldr + col]);
        C[(size_t)(rowb + i) * ldc + col] = __float2bfloat16(v);
      }
    }
  }
}

// ---------------------------------------------------------------------------
// Window-5 causal attention, one WAVE per token. lane = h*4 + c. Scores stay
// register-local; in-place into q-cols (wave t is the sole reader of q[t]).
// ---------------------------------------------------------------------------
__global__ __launch_bounds__(256) void attn_win(bf16* __restrict__ qkv)
{
  const int lane = threadIdx.x & 63;
  const int tk   = blockIdx.x * 4 + (threadIdx.x >> 6);   // token 0..4095
  const int s    = tk & 2047;                             // pos in sequence
  const int doff = (lane >> 2) * 64 + (lane & 3) * 16;    // h*64 + c*16

  const size_t row = (size_t)tk * 3072;

  bf16x8 qa = *(const bf16x8*)&qkv[row + doff];
  bf16x8 qb = *(const bf16x8*)&qkv[row + doff + 8];
  float qf[16];
  #pragma unroll
  for (int e = 0; e < 8; ++e) { qf[e] = b2f(qa[e]); qf[8 + e] = b2f(qb[e]); }

  const int W = (s + 1 < 5) ? (s + 1) : 5;
  float p[5];
  #pragma unroll
  for (int j = 0; j < 5; ++j) {
    const int jc = (j < W) ? j : 0;                       // clamped (valid addr)
    const size_t kr = row - (size_t)jc * 3072 + 1024;
    bf16x8 ka = *(const bf16x8*)&qkv[kr + doff];
    bf16x8 kb = *(const bf16x8*)&qkv[kr + doff + 8];
    float d = 0.f;
    #pragma unroll
    for (int e = 0; e < 8; ++e) d += qf[e] * b2f(ka[e]);
    #pragma unroll
    for (int e = 0; e < 8; ++e) d += qf[8 + e] * b2f(kb[e]);
    d += __shfl_xor(d, 1);
    d += __shfl_xor(d, 2);
    p[j] = (j < W) ? d * 0.125f : -1e30f;                 // 1/sqrt(64); mask
  }

  float mx = fmaxf(fmaxf(fmaxf(p[0], p[1]), fmaxf(p[2], p[3])), p[4]);
  float sum = 0.f;
  #pragma unroll
  for (int j = 0; j < 5; ++j) { p[j] = __expf(p[j] - mx); sum += p[j]; }
  const float inv = 1.f / sum;

  float o[16];
  #pragma unroll
  for (int e = 0; e < 16; ++e) o[e] = 0.f;
  #pragma unroll
  for (int j = 0; j < 5; ++j) {
    const int jc = (j < W) ? j : 0;
    const size_t vr = row - (size_t)jc * 3072 + 2048;
    bf16x8 va = *(const bf16x8*)&qkv[vr + doff];
    bf16x8 vb = *(const bf16x8*)&qkv[vr + doff + 8];
    #pragma unroll
    for (int e = 0; e < 8; ++e) { o[e] += p[j] * b2f(va[e]); o[8 + e] += p[j] * b2f(vb[e]); }
  }

  bf16x8 oa, ob;
  #pragma unroll
  for (int e = 0; e < 8; ++e) {
    oa[e] = (short)__bfloat16_as_ushort(__float2bfloat16(o[e] * inv));
    ob[e] = (short)__bfloat16_as_ushort(__float2bfloat16(o[8 + e] * inv));
  }
  *(bf16x8*)&qkv[row + doff]     = oa;
  *(bf16x8*)&qkv[row + doff + 8] = ob;
}

// ---------------------------------------------------------------------------
// Fused split-K reduce + residual + bias + LayerNorm over dim=1024.
// ---------------------------------------------------------------------------
template<int OUTF32, int RESBF16>
__global__ __launch_bounds__(256) void ln_fuse(
    const bf16* __restrict__ P0, const bf16* __restrict__ P1, int ldp,
    const void* __restrict__ Rv,
    const float* __restrict__ bias,
    const float* __restrict__ g, const float* __restrict__ bt,
    void* __restrict__ outv)
{
  const int tk   = blockIdx.x * 4 + (threadIdx.x >> 6);
  const int lane = threadIdx.x & 63;
  const size_t bp = (size_t)tk * ldp;
  const size_t bo = (size_t)tk * 1024;

  float v[16];
  float sum = 0.f;
  #pragma unroll
  for (int i = 0; i < 16; ++i) {
    const int e = i * 64 + lane;
    float t = __bfloat162float(P0[bp + e]) + __bfloat162float(P1[bp + e]) + bias[e];
    if (RESBF16) t += __bfloat162float(((const bf16*)Rv)[bo + e]);
    else         t += ((const float*)Rv)[bo + e];
    v[i] = t;
    sum += t;
  }
  #pragma unroll
  for (int d = 1; d < 64; d <<= 1) sum += __shfl_xor(sum, d);
  const float mu = sum * (1.f / 1024.f);

  float sq = 0.f;
  #pragma unroll
  for (int i = 0; i < 16; ++i) { const float dv = v[i] - mu; sq += dv * dv; }
  #pragma unroll
  for (int d = 1; d < 64; d <<= 1) sq += __shfl_xor(sq, d);
  const float rstd = rsqrtf(sq * (1.f / 1024.f) + 1e-5f);

  #pragma unroll
  for (int i = 0; i < 16; ++i) {
    const int e = i * 64 + lane;
    const float o = (v[i] - mu) * rstd * g[e] + bt[e];
    if (OUTF32) ((float*)outv)[bo + e] = o;
    else        ((bf16*)outv)[bo + e] = __float2bfloat16(o);
  }
}

// ---------------------------------------------------------------------------
// WS layout (75.5 MB):
//   0        : qkv [4096,3072] bf16 / phase2: h [4096,4096]
//   33554432 : x_b [4096,1024] -> GEMM6 partial P0
//   41943040 : x1_b [4096,1024]
//   50331648 : w1_b [4096,1024] -> GEMM6 partial P1
//   58720256 : w2_b [1024,4096]
//   67108864 : w_in_b [3072,1024]
//   73400320 : w_out_b [1024,1024]
// ---------------------------------------------------------------------------
extern "C" void kernel_launch(void* const* d_in, const int* in_sizes, int n_in,
                              void* d_out, int out_size, void* d_ws, size_t ws_size,
                              hipStream_t stream)
{
  const float* x     = (const float*)d_in[0];
  const float* w_in  = (const float*)d_in[1];
  const float* b_in  = (const float*)d_in[2];
  const float* w_out = (const float*)d_in[3];
  const float* b_out = (const float*)d_in[4];
  const float* ln1_g = (const float*)d_in[5];
  const float* ln1_b = (const float*)d_in[6];
  const float* ln2_g = (const float*)d_in[7];
  const float* ln2_b = (const float*)d_in[8];
  const float* w1    = (const float*)d_in[9];
  const float* b1    = (const float*)d_in[10];
  const float* w2    = (const float*)d_in[11];
  const float* b2    = (const float*)d_in[12];
  float* out = (float*)d_out;

  char* ws = (char*)d_ws;
  bf16* qkv     = (bf16*)(ws);
  bf16* h       = (bf16*)(ws);
  bf16* x_b     = (bf16*)(ws + 33554432);
  bf16* x1_b    = (bf16*)(ws + 41943040);
  bf16* w1_b    = (bf16*)(ws + 50331648);
  bf16* w2_b    = (bf16*)(ws + 58720256);
  bf16* w_in_b  = (bf16*)(ws + 67108864);
  bf16* w_out_b = (bf16*)(ws + 73400320);
  bf16* P0      = x_b;
  bf16* P1      = w1_b;

  const dim3 blk(256);
  const dim3 blk512(512);

  // 0) fp32 -> bf16 operand conversion (single dispatch)
  cvt_all<<<dim3(16384), blk, 0, stream>>>(x, w_in, w_out, w1, w2,
                                           x_b, w_in_b, w_out_b, w1_b, w2_b);

  // 1) qkv = x @ w_in^T + b_in                      [4096,3072]
  gemm8p<0,0><<<dim3(12, 32, 1), blk512, 0, stream>>>(
      x_b, 1024, w_in_b, 1024, b_in, nullptr, 0, qkv, 3072, 0, 1024);
  // 2) windowed causal attention, in-place into q-cols (wave per token)
  attn_win<<<dim3(1024), blk, 0, stream>>>(qkv);
  // 3) split-K=2: k-cols/v-cols = attn @ w_out^T partials (256 blocks)
  gemm8p<0,0><<<dim3(4, 32, 2), blk512, 0, stream>>>(
      qkv, 3072, w_out_b, 1024, nullptr, nullptr, 0,
      qkv + 1024, 3072, 1024, 512);
  // 4) x1_b = LN(x + P0 + P1 + b_out)
  ln_fuse<0,0><<<dim3(1024), blk, 0, stream>>>(
      qkv + 1024, qkv + 2048, 3072, x, b_out, ln1_g, ln1_b, x1_b);
  // 5) h = gelu(x1 @ w1^T + b1)                     [4096,4096]
  gemm8p<1,0><<<dim3(16, 32, 1), blk512, 0, stream>>>(
      x1_b, 1024, w1_b, 1024, b1, nullptr, 0, h, 4096, 0, 1024);
  // 6) split-K=2: P0/P1 = h @ w2^T partials (256 blocks)
  gemm8p<0,0><<<dim3(4, 32, 2), blk512, 0, stream>>>(
      h, 4096, w2_b, 4096, nullptr, nullptr, 0,
      P0, 1024, 8388608, 2048);
  // 7) out(fp32) = LN(x1 + P0 + P1 + b2)
  ln_fuse<1,1><<<dim3(1024), blk, 0, stream>>>(
      P0, P1, 1024, x1_b, b2, ln2_g, ln2_b, out);
}